// Round 16
// baseline (1499.953 us; speedup 1.0000x reference)
//
#include <hip/hip_runtime.h>
#include <cstddef>
#include <cstdint>

#define N_NODES 20000
#define N_EDGES 320000
#define NDAYS 4
#define LOOKBACK 7
#define NFEAT 5
#define XROW (LOOKBACK * NFEAT)  // 35
#define HIDDEN 128
#define GRUROWS 64  // rows per k_megagru block (4 tiles of 16); guards handle non-multiple tails

typedef short bf8 __attribute__((ext_vector_type(8)));
typedef float fx4 __attribute__((ext_vector_type(4)));

__device__ __forceinline__ float bflo(unsigned int u) {
    union { unsigned int u; float f; } v; v.u = u << 16; return v.f;
}
__device__ __forceinline__ float bfhi(unsigned int u) {
    union { unsigned int u; float f; } v; v.u = u & 0xffff0000u; return v.f;
}
__device__ __forceinline__ unsigned short f2bf(float f) {
    union { float f; unsigned int u; } v; v.f = f;
    unsigned int u = v.u + 0x7fffu + ((v.u >> 16) & 1u);
    return (unsigned short)(u >> 16);
}
__device__ __forceinline__ unsigned int packbf(float a, float b) {
    return (unsigned int)f2bf(a) | ((unsigned int)f2bf(b) << 16);
}
__device__ __forceinline__ float sigm(float v) { return 1.0f / (1.0f + __expf(-v)); }
__device__ __forceinline__ float ftanh(float v) {
    float e2 = __expf(2.0f * v);
    return (e2 - 1.0f) / (e2 + 1.0f);
}
__device__ __forceinline__ void accum8(float* a, uint4 v, float w) {
    a[0] += w * bflo(v.x); a[1] += w * bfhi(v.x);
    a[2] += w * bflo(v.y); a[3] += w * bfhi(v.y);
    a[4] += w * bflo(v.z); a[5] += w * bfhi(v.z);
    a[6] += w * bflo(v.w); a[7] += w * bfhi(v.w);
}

// ---------------- graph preprocessing ----------------

__global__ __launch_bounds__(256) void k_deg(const int* __restrict__ ei, int* __restrict__ deg) {
    int e = blockIdx.x * 256 + threadIdx.x;
    if (e < N_EDGES) atomicAdd(&deg[ei[N_EDGES + e]], 1);
}

__global__ __launch_bounds__(1024) void k_scan(const int* __restrict__ deg, int* __restrict__ row_start) {
    __shared__ int part[1024];
    int tid = threadIdx.x;
    const int chunk = (N_NODES + 1023) / 1024;  // 20
    int i0 = tid * chunk;
    int i1 = min(i0 + chunk, N_NODES);
    int s = 0;
    for (int i = i0; i < i1; ++i) s += deg[i];
    part[tid] = s;
    __syncthreads();
    for (int d = 1; d < 1024; d <<= 1) {
        int v = (tid >= d) ? part[tid - d] : 0;
        __syncthreads();
        part[tid] += v;
        __syncthreads();
    }
    int base = part[tid] - s;  // exclusive prefix
    for (int i = i0; i < i1; ++i) { row_start[i] = base; base += deg[i]; }
    if (tid == 1023) row_start[N_NODES] = part[1023];
}

__global__ __launch_bounds__(256) void k_dinv(const int* __restrict__ deg, float* __restrict__ dinv,
                                              float* __restrict__ self_norm) {
    int i = blockIdx.x * 256 + threadIdx.x;
    if (i >= N_NODES) return;
    float d = (float)(deg[i] + 1);
    dinv[i] = 1.0f / sqrtf(d);
    self_norm[i] = 1.0f / d;
}

__global__ __launch_bounds__(256) void k_fill(const int* __restrict__ ei, const int* __restrict__ row_start,
                                              int* __restrict__ cursor, const float* __restrict__ dinv,
                                              int* __restrict__ csr_src, float* __restrict__ csr_norm) {
    int e = blockIdx.x * 256 + threadIdx.x;
    if (e >= N_EDGES) return;
    int s = ei[e], d = ei[N_EDGES + e];
    int pos = row_start[d] + atomicAdd(&cursor[d], 1);
    csr_src[pos] = s;
    csr_norm[pos] = dinv[s] * dinv[d];
}

// W2T_bf[c][k] = bf16(W2[k][c])
__global__ __launch_bounds__(256) void k_w2t(const float* __restrict__ W2, unsigned short* __restrict__ W2T) {
    int idx = blockIdx.x * 256 + threadIdx.x;
    if (idx >= HIDDEN * HIDDEN) return;
    int k = idx >> 7, c = idx & 127;
    W2T[c * HIDDEN + k] = f2bf(W2[k * HIDDEN + c]);
}

__global__ __launch_bounds__(256) void k_cast(const float* __restrict__ src, unsigned short* __restrict__ dst, int n) {
    int i = blockIdx.x * 256 + threadIdx.x;
    if (i < n) dst[i] = f2bf(src[i]);
}

// b_fold[j] = b_ih[j] + b_hh[j] for r,z gates (j<256); b_ih[j] only for n gate
__global__ __launch_bounds__(256) void k_bfold(const float* __restrict__ b_ih, const float* __restrict__ b_hh,
                                               float* __restrict__ b_fold) {
    int i = blockIdx.x * 256 + threadIdx.x;
    if (i < 3 * HIDDEN) b_fold[i] = b_ih[i] + (i < 2 * HIDDEN ? b_hh[i] : 0.0f);
}

// ---------------- feature-space aggregation: xa[node*NB+b] = agg(x)[day b] ----------------

template<int NB>
__global__ __launch_bounds__(256) void k_aggx(const float* __restrict__ x, float* __restrict__ xa,
                                              const int* __restrict__ row_start, const int* __restrict__ csr_src,
                                              const float* __restrict__ csr_norm,
                                              const float* __restrict__ self_norm, int dayBase) {
    int n = blockIdx.x * 4 + (threadIdx.x >> 6);
    if (n >= N_NODES) return;
    int lane = threadIdx.x & 63;
    if (lane >= XROW) return;
    float sn = self_norm[n];
    float acc[NB];
#pragma unroll
    for (int b = 0; b < NB; ++b)
        acc[b] = x[(size_t)((dayBase + b) * N_NODES + n) * XROW + lane] * sn;
    int e1 = row_start[n + 1];
    for (int e = row_start[n]; e < e1; ++e) {
        int s = csr_src[e];
        float w = csr_norm[e];
#pragma unroll
        for (int b = 0; b < NB; ++b)
            acc[b] += w * x[(size_t)((dayBase + b) * N_NODES + s) * XROW + lane];
    }
#pragma unroll
    for (int b = 0; b < NB; ++b)
        xa[(size_t)(n * NB + b) * XROW + lane] = acc[b];
}

// ---------------- fused Z1+GEMM: H2 = relu(xa_t @ W1 + b1) @ W2  (out bf16 row-major) ----------------

__global__ __launch_bounds__(256) void k_z1gemm(const float* __restrict__ xa, const float* __restrict__ W1,
                                                const float* __restrict__ b1,
                                                const unsigned short* __restrict__ W2T,
                                                unsigned short* __restrict__ H2, int rows, int t) {
    int tid = threadIdx.x, w = tid >> 6, l = tid & 63, lr = l & 15, lk = l >> 4;
    int rblk = blockIdx.x * 64;
    int rowA = rblk + w * 16 + lr;
    bool okA = rowA < rows;
    float x5[5];
#pragma unroll
    for (int k = 0; k < 5; ++k)
        x5[k] = okA ? xa[(size_t)rowA * XROW + t * NFEAT + k] : 0.0f;
    bf8 az[4];
#pragma unroll
    for (int ks = 0; ks < 4; ++ks) {
#pragma unroll
        for (int j = 0; j < 8; ++j) {
            int ch = 32 * ks + 8 * lk + j;
            float v = b1[ch] + x5[0] * W1[ch] + x5[1] * W1[128 + ch] + x5[2] * W1[256 + ch]
                    + x5[3] * W1[384 + ch] + x5[4] * W1[512 + ch];
            az[ks][j] = (short)f2bf(fmaxf(v, 0.0f));
        }
    }
    const bf8* Bp = (const bf8*)W2T;
    fx4 acc[8];
#pragma unroll
    for (int n = 0; n < 8; ++n) acc[n] = (fx4){0.f, 0.f, 0.f, 0.f};
#pragma unroll
    for (int ks = 0; ks < 4; ++ks) {
#pragma unroll
        for (int n = 0; n < 8; ++n) {
            bf8 b = Bp[(size_t)(16 * n + lr) * 16 + 4 * ks + lk];
            acc[n] = __builtin_amdgcn_mfma_f32_16x16x32_bf16(az[ks], b, acc[n], 0, 0, 0);
        }
    }
#pragma unroll
    for (int n = 0; n < 8; ++n)
#pragma unroll
        for (int r = 0; r < 4; ++r) {
            int row = rblk + w * 16 + lk * 4 + r;
            if (row < rows) H2[(size_t)row * HIDDEN + 16 * n + lr] = f2bf(acc[n][r]);
        }
}

// ---------------- hidden-space aggregation, day-interleaved layout ----------------

template<int NB>
__global__ __launch_bounds__(256) void k_agg(const uint4* __restrict__ H, uint4* __restrict__ Z,
                                             const float* __restrict__ bias,
                                             const int* __restrict__ row_start, const int* __restrict__ csr_src,
                                             const float* __restrict__ csr_norm,
                                             const float* __restrict__ self_norm) {
    int n = blockIdx.x * 4 + (threadIdx.x >> 6);
    if (n >= N_NODES) return;
    int l = threadIdx.x & 63;
    if (l >= NB * 16) return;
    int c0 = (l & 15) * 8;
    float sn = self_norm[n];
    float a[8];
    {
        uint4 sv = H[(size_t)n * (NB * 16) + l];
        a[0] = bflo(sv.x) * sn; a[1] = bfhi(sv.x) * sn;
        a[2] = bflo(sv.y) * sn; a[3] = bfhi(sv.y) * sn;
        a[4] = bflo(sv.z) * sn; a[5] = bfhi(sv.z) * sn;
        a[6] = bflo(sv.w) * sn; a[7] = bfhi(sv.w) * sn;
    }
    int e1 = row_start[n + 1];
    int e = row_start[n];
    for (; e + 3 < e1; e += 4) {
        int s0 = csr_src[e], s1 = csr_src[e + 1], s2 = csr_src[e + 2], s3 = csr_src[e + 3];
        float w0 = csr_norm[e], w1 = csr_norm[e + 1], w2 = csr_norm[e + 2], w3 = csr_norm[e + 3];
        uint4 v0 = H[(size_t)s0 * (NB * 16) + l];
        uint4 v1 = H[(size_t)s1 * (NB * 16) + l];
        uint4 v2 = H[(size_t)s2 * (NB * 16) + l];
        uint4 v3 = H[(size_t)s3 * (NB * 16) + l];
        accum8(a, v0, w0); accum8(a, v1, w1); accum8(a, v2, w2); accum8(a, v3, w3);
    }
    for (; e < e1; ++e) {
        int s = csr_src[e];
        float w = csr_norm[e];
        uint4 v = H[(size_t)s * (NB * 16) + l];
        accum8(a, v, w);
    }
    const float* bp = bias + c0;
    uint4 o;
    o.x = packbf(fmaxf(a[0] + bp[0], 0.f), fmaxf(a[1] + bp[1], 0.f));
    o.y = packbf(fmaxf(a[2] + bp[2], 0.f), fmaxf(a[3] + bp[3], 0.f));
    o.z = packbf(fmaxf(a[4] + bp[4], 0.f), fmaxf(a[5] + bp[5], 0.f));
    o.w = packbf(fmaxf(a[6] + bp[6], 0.f), fmaxf(a[7] + bp[7], 0.f));
    Z[(size_t)n * (NB * 16) + l] = o;
}

// ---------------- mega GRU v8: v6 body, Whh fragments from L2-hot GLOBAL (no wlds) ->
// LDS = 32KB (h-exchange only) + VGPR<=128 -> 2 blocks/CU resident; inter-block TLP hides
// az/L3 latency and barrier tails. Bh reads hoisted per t, reused by 4 m-tiles. ----------------

template<bool FIRST>
__global__ __launch_bounds__(512, 4) void k_megagru(const unsigned short* __restrict__ Z2all,
                                                    float* __restrict__ Hf,
                                                    const unsigned short* __restrict__ Wih,
                                                    const unsigned short* __restrict__ Whh,
                                                    const float* __restrict__ bfold,
                                                    const float* __restrict__ bhh, int rows, int NT) {
    __shared__ __align__(16) char hlds[2 * GRUROWS * 256];  // 32 KB h double-buffer
    const int HALF = GRUROWS * 256;                          // 16384 B
    int tid = threadIdx.x, w = tid >> 6, l = tid & 63, lr = l & 15, lk = l >> 4;
    int row0 = blockIdx.x * GRUROWS;
    int c = w * 16 + lr;

    // Wih fragments (12 x 4 VGPR); compiler may hoist or rematerialize (L2-hot either way)
    bf8 Bi[3][4];
    const bf8* BiP = (const bf8*)Wih;
#pragma unroll
    for (int g = 0; g < 3; ++g)
#pragma unroll
        for (int ks = 0; ks < 4; ++ks)
            Bi[g][ks] = BiP[(size_t)(g * HIDDEN + c) * 16 + 4 * ks + lk];
    const bf8* BhP = (const bf8*)Whh;

    float bf_r = bfold[c], bf_z = bfold[HIDDEN + c], bf_n = bfold[2 * HIDDEN + c];
    float bh_n = bhh[2 * HIDDEN + c];

    float hreg[4][4];
    if (FIRST) {
#pragma unroll
        for (int m = 0; m < 4; ++m)
#pragma unroll
            for (int r = 0; r < 4; ++r) hreg[m][r] = 0.f;
        for (int i = tid; i < HALF / 4; i += 512) ((unsigned int*)hlds)[i] = 0u;
    } else {
#pragma unroll
        for (int m = 0; m < 4; ++m)
#pragma unroll
            for (int r = 0; r < 4; ++r) {
                int row = 16 * m + lk * 4 + r;
                int grow = row0 + row;
                float h = (grow < rows) ? Hf[(size_t)grow * HIDDEN + c] : 0.0f;
                hreg[m][r] = h;
                int byte = row * 256 + ((c * 2) ^ ((row & 15) << 4));
                *(unsigned short*)(hlds + byte) = f2bf(h);
            }
    }
    __syncthreads();  // init barrier (h buffer 0 visible)

    for (int t = 0; t < NT; ++t) {
        const int p = t & 1;
        const unsigned short* z2t = Z2all + ((size_t)t * rows + row0) * HIDDEN;

        // Whh fragments for this wave's 16-col slice: from L2-hot global, once per t,
        // reused by all 4 m-tiles (12 loads issued as a batch)
        bf8 bwR[4], bwZ[4], bwN[4];
#pragma unroll
        for (int ks = 0; ks < 4; ++ks) {
            bwR[ks] = BhP[(size_t)(0 * HIDDEN + c) * 16 + 4 * ks + lk];
            bwZ[ks] = BhP[(size_t)(1 * HIDDEN + c) * 16 + 4 * ks + lk];
            bwN[ks] = BhP[(size_t)(2 * HIDDEN + c) * 16 + 4 * ks + lk];
        }

#pragma unroll
        for (int m = 0; m < 4; ++m) {
            int rowA = row0 + 16 * m + lr;
            bool okA = rowA < rows;
            bf8 az[4];
            const bf8* zp = (const bf8*)(z2t + (size_t)(16 * m + lr) * HIDDEN);
#pragma unroll
            for (int ks = 0; ks < 4; ++ks)
                az[ks] = okA ? zp[4 * ks + lk] : (bf8){0, 0, 0, 0, 0, 0, 0, 0};
            bf8 ah[4];
#pragma unroll
            for (int ks = 0; ks < 4; ++ks) {
                int byte = p * HALF + (16 * m + lr) * 256 + ((ks * 64 + lk * 16) ^ (lr << 4));
                ah[ks] = *(const bf8*)(hlds + byte);
            }
            fx4 aR = (fx4){0.f, 0.f, 0.f, 0.f};
            fx4 aZ = (fx4){0.f, 0.f, 0.f, 0.f};
            fx4 aNi = (fx4){0.f, 0.f, 0.f, 0.f};
            fx4 aNh = (fx4){0.f, 0.f, 0.f, 0.f};
#pragma unroll
            for (int ks = 0; ks < 4; ++ks) {
                aR = __builtin_amdgcn_mfma_f32_16x16x32_bf16(ah[ks], bwR[ks], aR, 0, 0, 0);
                aZ = __builtin_amdgcn_mfma_f32_16x16x32_bf16(ah[ks], bwZ[ks], aZ, 0, 0, 0);
                aNh = __builtin_amdgcn_mfma_f32_16x16x32_bf16(ah[ks], bwN[ks], aNh, 0, 0, 0);
            }
#pragma unroll
            for (int ks = 0; ks < 4; ++ks) {
                aR = __builtin_amdgcn_mfma_f32_16x16x32_bf16(az[ks], Bi[0][ks], aR, 0, 0, 0);
                aZ = __builtin_amdgcn_mfma_f32_16x16x32_bf16(az[ks], Bi[1][ks], aZ, 0, 0, 0);
                aNi = __builtin_amdgcn_mfma_f32_16x16x32_bf16(az[ks], Bi[2][ks], aNi, 0, 0, 0);
            }
#pragma unroll
            for (int r = 0; r < 4; ++r) {
                int row = 16 * m + lk * 4 + r;
                float rr = sigm(aR[r] + bf_r);
                float zz = sigm(aZ[r] + bf_z);
                float nn = ftanh(aNi[r] + bf_n + rr * (aNh[r] + bh_n));
                float hnew = (1.0f - zz) * nn + zz * hreg[m][r];
                hreg[m][r] = hnew;
                int byte = (p ^ 1) * HALF + row * 256 + ((c * 2) ^ ((row & 15) << 4));
                *(unsigned short*)(hlds + byte) = f2bf(hnew);
            }
        }
        // LDS-only fence + barrier (no vmcnt drain)
        asm volatile("s_waitcnt lgkmcnt(0)" ::: "memory");
        __builtin_amdgcn_s_barrier();
        __builtin_amdgcn_sched_barrier(0);
    }

#pragma unroll
    for (int m = 0; m < 4; ++m)
#pragma unroll
        for (int r = 0; r < 4; ++r) {
            int grow = row0 + 16 * m + lk * 4 + r;
            if (grow < rows) Hf[(size_t)grow * HIDDEN + c] = hreg[m][r];
        }
}

// ---------------- output head: softmax(h @ W_out + b_out) ----------------

template<int NB>
__global__ __launch_bounds__(256) void k_out(const float* __restrict__ Hc, const float* __restrict__ Wo,
                                             const float* __restrict__ bo, float* __restrict__ out,
                                             int dayBase) {
    int rr = blockIdx.x * 4 + (threadIdx.x >> 6);
    if (rr >= N_NODES * NB) return;
    int lane = threadIdx.x & 63;
    float2 hv = ((const float2*)(Hc + (size_t)rr * HIDDEN))[lane];
    float l[5];
#pragma unroll
    for (int j = 0; j < 5; ++j) {
        float p = hv.x * Wo[(2 * lane) * 5 + j] + hv.y * Wo[(2 * lane + 1) * 5 + j];
#pragma unroll
        for (int s = 1; s < 64; s <<= 1) p += __shfl_xor(p, s);
        l[j] = p + bo[j];
    }
    float m = fmaxf(fmaxf(fmaxf(l[0], l[1]), fmaxf(l[2], l[3])), l[4]);
    float e0 = expf(l[0] - m), e1 = expf(l[1] - m), e2 = expf(l[2] - m), e3 = expf(l[3] - m), e4 = expf(l[4] - m);
    float inv = 1.0f / (e0 + e1 + e2 + e3 + e4);
    if (lane < 5) {
        float ej = lane == 0 ? e0 : lane == 1 ? e1 : lane == 2 ? e2 : lane == 3 ? e3 : e4;
        int n = rr / NB, dd = dayBase + rr % NB;
        out[((size_t)dd * N_NODES + n) * 5 + lane] = ej * inv;
    }
}

// ---------------- per-tier pipeline (Z2 staged 4 timesteps at a time; h checkpointed in Hf f32) ----------------

template<int NB>
static void run_tier(const float* x, const float* W1, const float* b1,
                     const unsigned short* W2T_bf, const float* b2,
                     const unsigned short* Wih_bf, const unsigned short* Whh_bf,
                     const float* b_fold, const float* b_hh,
                     const float* W_out, const float* b_out, float* out,
                     const int* row_start, const int* csr_src, const float* csr_norm,
                     const float* self_norm,
                     float* xa, unsigned short* H2, unsigned short* Z2all, float* Hf,
                     hipStream_t stream) {
    const int rows = N_NODES * NB;
    const unsigned ngrid = (N_NODES + 3) / 4;
    const unsigned gblk = (unsigned)((rows + 63) / 64);
    const unsigned gru_grid = (unsigned)((rows + GRUROWS - 1) / GRUROWS);
    const int rounds = NDAYS / NB;
    for (int dd = 0; dd < rounds; ++dd) {
        int dayBase = dd * NB;
        k_aggx<NB><<<ngrid, 256, 0, stream>>>(x, xa, row_start, csr_src, csr_norm, self_norm, dayBase);
        for (int t = 0; t < 4; ++t) {
            k_z1gemm<<<gblk, 256, 0, stream>>>(xa, W1, b1, W2T_bf, H2, rows, t);
            k_agg<NB><<<ngrid, 256, 0, stream>>>((const uint4*)H2,
                                                 (uint4*)(Z2all + (size_t)t * rows * HIDDEN), b2,
                                                 row_start, csr_src, csr_norm, self_norm);
        }
        k_megagru<true><<<gru_grid, 512, 0, stream>>>(Z2all, Hf, Wih_bf, Whh_bf, b_fold, b_hh, rows, 4);
        for (int t = 4; t < LOOKBACK; ++t) {
            k_z1gemm<<<gblk, 256, 0, stream>>>(xa, W1, b1, W2T_bf, H2, rows, t);
            k_agg<NB><<<ngrid, 256, 0, stream>>>((const uint4*)H2,
                                                 (uint4*)(Z2all + (size_t)(t - 4) * rows * HIDDEN), b2,
                                                 row_start, csr_src, csr_norm, self_norm);
        }
        k_megagru<false><<<gru_grid, 512, 0, stream>>>(Z2all, Hf, Wih_bf, Whh_bf, b_fold, b_hh, rows, 3);
        k_out<NB><<<(unsigned)((rows + 3) / 4), 256, 0, stream>>>(Hf, W_out, b_out, out, dayBase);
    }
}

// ---------------- launch ----------------

extern "C" void kernel_launch(void* const* d_in, const int* in_sizes, int n_in,
                              void* d_out, int out_size, void* d_ws, size_t ws_size,
                              hipStream_t stream) {
    const float* x     = (const float*)d_in[0];
    const int*   ei    = (const int*)d_in[1];
    const float* W1    = (const float*)d_in[2];
    const float* b1    = (const float*)d_in[3];
    const float* W2    = (const float*)d_in[4];
    const float* b2    = (const float*)d_in[5];
    const float* W_ih  = (const float*)d_in[6];
    const float* W_hh  = (const float*)d_in[7];
    const float* b_ih  = (const float*)d_in[8];
    const float* b_hh  = (const float*)d_in[9];
    const float* W_out = (const float*)d_in[10];
    const float* b_out = (const float*)d_in[11];
    float* out = (float*)d_out;

    size_t off = 0;
    char* wsb = (char*)d_ws;
    auto alloc = [&](size_t bytes) -> void* {
        void* p = wsb + off;
        off = (off + bytes + 255) & ~(size_t)255;
        return p;
    };
    int*            deg       = (int*)alloc(N_NODES * 4);
    int*            cursor    = (int*)alloc(N_NODES * 4);
    int*            row_start = (int*)alloc((N_NODES + 1) * 4);
    float*          dinv      = (float*)alloc(N_NODES * 4);
    float*          self_norm = (float*)alloc(N_NODES * 4);
    unsigned short* W2T_bf    = (unsigned short*)alloc(HIDDEN * HIDDEN * 2);
    unsigned short* Wih_bf    = (unsigned short*)alloc(3 * HIDDEN * HIDDEN * 2);
    unsigned short* Whh_bf    = (unsigned short*)alloc(3 * HIDDEN * HIDDEN * 2);
    float*          b_fold    = (float*)alloc(3 * HIDDEN * 4);
    int*            csr_src   = (int*)alloc(N_EDGES * 4);
    float*          csr_norm  = (float*)alloc(N_EDGES * 4);

    // per-row bytes: xa 140 + H2 256 + Z2all 4*256 + Hf 512 = 1932
    size_t prep_off = off;
    auto need = [&](int nb) -> size_t {
        return prep_off + (size_t)N_NODES * nb * 1932 + 16384;
    };
    int NBsel = (need(4) <= ws_size) ? 4 : (need(2) <= ws_size) ? 2 : 1;
    int rows = N_NODES * NBsel;

    float*          xa    = (float*)alloc((size_t)rows * XROW * 4);
    unsigned short* H2    = (unsigned short*)alloc((size_t)rows * HIDDEN * 2);
    unsigned short* Z2all = (unsigned short*)alloc((size_t)4 * rows * HIDDEN * 2);
    float*          Hf    = (float*)alloc((size_t)rows * HIDDEN * 4);

    // graph + weight prep
    hipMemsetAsync(deg, 0, N_NODES * 4, stream);
    hipMemsetAsync(cursor, 0, N_NODES * 4, stream);
    k_deg<<<(N_EDGES + 255) / 256, 256, 0, stream>>>(ei, deg);
    k_scan<<<1, 1024, 0, stream>>>(deg, row_start);
    k_dinv<<<(N_NODES + 255) / 256, 256, 0, stream>>>(deg, dinv, self_norm);
    k_fill<<<(N_EDGES + 255) / 256, 256, 0, stream>>>(ei, row_start, cursor, dinv, csr_src, csr_norm);
    k_w2t<<<(HIDDEN * HIDDEN + 255) / 256, 256, 0, stream>>>(W2, W2T_bf);
    k_cast<<<(3 * HIDDEN * HIDDEN + 255) / 256, 256, 0, stream>>>(W_ih, Wih_bf, 3 * HIDDEN * HIDDEN);
    k_cast<<<(3 * HIDDEN * HIDDEN + 255) / 256, 256, 0, stream>>>(W_hh, Whh_bf, 3 * HIDDEN * HIDDEN);
    k_bfold<<<2, 256, 0, stream>>>(b_ih, b_hh, b_fold);

    if (NBsel == 4)
        run_tier<4>(x, W1, b1, W2T_bf, b2, Wih_bf, Whh_bf, b_fold, b_hh, W_out, b_out, out,
                    row_start, csr_src, csr_norm, self_norm, xa, H2, Z2all, Hf, stream);
    else if (NBsel == 2)
        run_tier<2>(x, W1, b1, W2T_bf, b2, Wih_bf, Whh_bf, b_fold, b_hh, W_out, b_out, out,
                    row_start, csr_src, csr_norm, self_norm, xa, H2, Z2all, Hf, stream);
    else
        run_tier<1>(x, W1, b1, W2T_bf, b2, Wih_bf, Whh_bf, b_fold, b_hh, W_out, b_out, out,
                    row_start, csr_src, csr_norm, self_norm, xa, H2, Z2all, Hf, stream);
}

// Round 18
// 959.929 us; speedup vs baseline: 1.5626x; 1.5626x over previous
//
#include <hip/hip_runtime.h>
#include <cstddef>
#include <cstdint>

#define N_NODES 20000
#define N_EDGES 320000
#define NDAYS 4
#define LOOKBACK 7
#define NFEAT 5
#define XROW (LOOKBACK * NFEAT)  // 35
#define HIDDEN 128
#define GRUROWS 64  // rows per k_megagru block (4 tiles of 16); guards handle non-multiple tails

typedef short bf8 __attribute__((ext_vector_type(8)));
typedef float fx4 __attribute__((ext_vector_type(4)));

__device__ __forceinline__ float bflo(unsigned int u) {
    union { unsigned int u; float f; } v; v.u = u << 16; return v.f;
}
__device__ __forceinline__ float bfhi(unsigned int u) {
    union { unsigned int u; float f; } v; v.u = u & 0xffff0000u; return v.f;
}
__device__ __forceinline__ unsigned short f2bf(float f) {
    union { float f; unsigned int u; } v; v.f = f;
    unsigned int u = v.u + 0x7fffu + ((v.u >> 16) & 1u);
    return (unsigned short)(u >> 16);
}
__device__ __forceinline__ unsigned int packbf(float a, float b) {
    return (unsigned int)f2bf(a) | ((unsigned int)f2bf(b) << 16);
}
__device__ __forceinline__ float sigm(float v) { return 1.0f / (1.0f + __expf(-v)); }
__device__ __forceinline__ float ftanh(float v) {
    float e2 = __expf(2.0f * v);
    return (e2 - 1.0f) / (e2 + 1.0f);
}
__device__ __forceinline__ void accum8(float* a, uint4 v, float w) {
    a[0] += w * bflo(v.x); a[1] += w * bfhi(v.x);
    a[2] += w * bflo(v.y); a[3] += w * bfhi(v.y);
    a[4] += w * bflo(v.z); a[5] += w * bfhi(v.z);
    a[6] += w * bflo(v.w); a[7] += w * bfhi(v.w);
}

// ---------------- graph preprocessing ----------------

__global__ __launch_bounds__(256) void k_deg(const int* __restrict__ ei, int* __restrict__ deg) {
    int e = blockIdx.x * 256 + threadIdx.x;
    if (e < N_EDGES) atomicAdd(&deg[ei[N_EDGES + e]], 1);
}

__global__ __launch_bounds__(1024) void k_scan(const int* __restrict__ deg, int* __restrict__ row_start) {
    __shared__ int part[1024];
    int tid = threadIdx.x;
    const int chunk = (N_NODES + 1023) / 1024;  // 20
    int i0 = tid * chunk;
    int i1 = min(i0 + chunk, N_NODES);
    int s = 0;
    for (int i = i0; i < i1; ++i) s += deg[i];
    part[tid] = s;
    __syncthreads();
    for (int d = 1; d < 1024; d <<= 1) {
        int v = (tid >= d) ? part[tid - d] : 0;
        __syncthreads();
        part[tid] += v;
        __syncthreads();
    }
    int base = part[tid] - s;  // exclusive prefix
    for (int i = i0; i < i1; ++i) { row_start[i] = base; base += deg[i]; }
    if (tid == 1023) row_start[N_NODES] = part[1023];
}

__global__ __launch_bounds__(256) void k_dinv(const int* __restrict__ deg, float* __restrict__ dinv,
                                              float* __restrict__ self_norm) {
    int i = blockIdx.x * 256 + threadIdx.x;
    if (i >= N_NODES) return;
    float d = (float)(deg[i] + 1);
    dinv[i] = 1.0f / sqrtf(d);
    self_norm[i] = 1.0f / d;
}

__global__ __launch_bounds__(256) void k_fill(const int* __restrict__ ei, const int* __restrict__ row_start,
                                              int* __restrict__ cursor, const float* __restrict__ dinv,
                                              int* __restrict__ csr_src, float* __restrict__ csr_norm) {
    int e = blockIdx.x * 256 + threadIdx.x;
    if (e >= N_EDGES) return;
    int s = ei[e], d = ei[N_EDGES + e];
    int pos = row_start[d] + atomicAdd(&cursor[d], 1);
    csr_src[pos] = s;
    csr_norm[pos] = dinv[s] * dinv[d];
}

// W2T_bf[c][k] = bf16(W2[k][c])
__global__ __launch_bounds__(256) void k_w2t(const float* __restrict__ W2, unsigned short* __restrict__ W2T) {
    int idx = blockIdx.x * 256 + threadIdx.x;
    if (idx >= HIDDEN * HIDDEN) return;
    int k = idx >> 7, c = idx & 127;
    W2T[c * HIDDEN + k] = f2bf(W2[k * HIDDEN + c]);
}

__global__ __launch_bounds__(256) void k_cast(const float* __restrict__ src, unsigned short* __restrict__ dst, int n) {
    int i = blockIdx.x * 256 + threadIdx.x;
    if (i < n) dst[i] = f2bf(src[i]);
}

// b_fold[j] = b_ih[j] + b_hh[j] for r,z gates (j<256); b_ih[j] only for n gate
__global__ __launch_bounds__(256) void k_bfold(const float* __restrict__ b_ih, const float* __restrict__ b_hh,
                                               float* __restrict__ b_fold) {
    int i = blockIdx.x * 256 + threadIdx.x;
    if (i < 3 * HIDDEN) b_fold[i] = b_ih[i] + (i < 2 * HIDDEN ? b_hh[i] : 0.0f);
}

// ---------------- feature-space aggregation: xa[node*NB+b] = agg(x)[day b] ----------------

template<int NB>
__global__ __launch_bounds__(256) void k_aggx(const float* __restrict__ x, float* __restrict__ xa,
                                              const int* __restrict__ row_start, const int* __restrict__ csr_src,
                                              const float* __restrict__ csr_norm,
                                              const float* __restrict__ self_norm, int dayBase) {
    int n = blockIdx.x * 4 + (threadIdx.x >> 6);
    if (n >= N_NODES) return;
    int lane = threadIdx.x & 63;
    if (lane >= XROW) return;
    float sn = self_norm[n];
    float acc[NB];
#pragma unroll
    for (int b = 0; b < NB; ++b)
        acc[b] = x[(size_t)((dayBase + b) * N_NODES + n) * XROW + lane] * sn;
    int e1 = row_start[n + 1];
    for (int e = row_start[n]; e < e1; ++e) {
        int s = csr_src[e];
        float w = csr_norm[e];
#pragma unroll
        for (int b = 0; b < NB; ++b)
            acc[b] += w * x[(size_t)((dayBase + b) * N_NODES + s) * XROW + lane];
    }
#pragma unroll
    for (int b = 0; b < NB; ++b)
        xa[(size_t)(n * NB + b) * XROW + lane] = acc[b];
}

// ---------------- fused Z1+GEMM (t-batched via blockIdx.y): H2all[y] = relu(xa_{t0+y} @ W1 + b1) @ W2 ----------------

__global__ __launch_bounds__(256) void k_z1gemm(const float* __restrict__ xa, const float* __restrict__ W1,
                                                const float* __restrict__ b1,
                                                const unsigned short* __restrict__ W2T,
                                                unsigned short* __restrict__ H2all, int rows, int t0) {
    int tid = threadIdx.x, w = tid >> 6, l = tid & 63, lr = l & 15, lk = l >> 4;
    int t = t0 + blockIdx.y;
    unsigned short* H2 = H2all + (size_t)blockIdx.y * rows * HIDDEN;
    int rblk = blockIdx.x * 64;
    int rowA = rblk + w * 16 + lr;
    bool okA = rowA < rows;
    float x5[5];
#pragma unroll
    for (int k = 0; k < 5; ++k)
        x5[k] = okA ? xa[(size_t)rowA * XROW + t * NFEAT + k] : 0.0f;
    bf8 az[4];
#pragma unroll
    for (int ks = 0; ks < 4; ++ks) {
#pragma unroll
        for (int j = 0; j < 8; ++j) {
            int ch = 32 * ks + 8 * lk + j;
            float v = b1[ch] + x5[0] * W1[ch] + x5[1] * W1[128 + ch] + x5[2] * W1[256 + ch]
                    + x5[3] * W1[384 + ch] + x5[4] * W1[512 + ch];
            az[ks][j] = (short)f2bf(fmaxf(v, 0.0f));
        }
    }
    const bf8* Bp = (const bf8*)W2T;
    fx4 acc[8];
#pragma unroll
    for (int n = 0; n < 8; ++n) acc[n] = (fx4){0.f, 0.f, 0.f, 0.f};
#pragma unroll
    for (int ks = 0; ks < 4; ++ks) {
#pragma unroll
        for (int n = 0; n < 8; ++n) {
            bf8 b = Bp[(size_t)(16 * n + lr) * 16 + 4 * ks + lk];
            acc[n] = __builtin_amdgcn_mfma_f32_16x16x32_bf16(az[ks], b, acc[n], 0, 0, 0);
        }
    }
#pragma unroll
    for (int n = 0; n < 8; ++n)
#pragma unroll
        for (int r = 0; r < 4; ++r) {
            int row = rblk + w * 16 + lk * 4 + r;
            if (row < rows) H2[(size_t)row * HIDDEN + 16 * n + lr] = f2bf(acc[n][r]);
        }
}

// ---------------- hidden-space aggregation (t-batched via blockIdx.y), day-interleaved layout ----------------

template<int NB>
__global__ __launch_bounds__(256) void k_agg(const uint4* __restrict__ H2all, uint4* __restrict__ Zall,
                                             const float* __restrict__ bias,
                                             const int* __restrict__ row_start, const int* __restrict__ csr_src,
                                             const float* __restrict__ csr_norm,
                                             const float* __restrict__ self_norm, int rows) {
    int n = blockIdx.x * 4 + (threadIdx.x >> 6);
    if (n >= N_NODES) return;
    int l = threadIdx.x & 63;
    if (l >= NB * 16) return;
    const uint4* H = H2all + (size_t)blockIdx.y * rows * 16;
    uint4* Z = Zall + (size_t)blockIdx.y * rows * 16;
    int c0 = (l & 15) * 8;
    float sn = self_norm[n];
    float a[8];
    {
        uint4 sv = H[(size_t)n * (NB * 16) + l];
        a[0] = bflo(sv.x) * sn; a[1] = bfhi(sv.x) * sn;
        a[2] = bflo(sv.y) * sn; a[3] = bfhi(sv.y) * sn;
        a[4] = bflo(sv.z) * sn; a[5] = bfhi(sv.z) * sn;
        a[6] = bflo(sv.w) * sn; a[7] = bfhi(sv.w) * sn;
    }
    int e1 = row_start[n + 1];
    int e = row_start[n];
    for (; e + 3 < e1; e += 4) {
        int s0 = csr_src[e], s1 = csr_src[e + 1], s2 = csr_src[e + 2], s3 = csr_src[e + 3];
        float w0 = csr_norm[e], w1 = csr_norm[e + 1], w2 = csr_norm[e + 2], w3 = csr_norm[e + 3];
        uint4 v0 = H[(size_t)s0 * (NB * 16) + l];
        uint4 v1 = H[(size_t)s1 * (NB * 16) + l];
        uint4 v2 = H[(size_t)s2 * (NB * 16) + l];
        uint4 v3 = H[(size_t)s3 * (NB * 16) + l];
        accum8(a, v0, w0); accum8(a, v1, w1); accum8(a, v2, w2); accum8(a, v3, w3);
    }
    for (; e < e1; ++e) {
        int s = csr_src[e];
        float w = csr_norm[e];
        uint4 v = H[(size_t)s * (NB * 16) + l];
        accum8(a, v, w);
    }
    const float* bp = bias + c0;
    uint4 o;
    o.x = packbf(fmaxf(a[0] + bp[0], 0.f), fmaxf(a[1] + bp[1], 0.f));
    o.y = packbf(fmaxf(a[2] + bp[2], 0.f), fmaxf(a[3] + bp[3], 0.f));
    o.z = packbf(fmaxf(a[4] + bp[4], 0.f), fmaxf(a[5] + bp[5], 0.f));
    o.w = packbf(fmaxf(a[6] + bp[6], 0.f), fmaxf(a[7] + bp[7], 0.f));
    Z[(size_t)n * (NB * 16) + l] = o;
}

// ---------------- mega GRU (R14 v6, measured best): Whh in swizzled LDS read once per t,
// GRUROWS=64 (4 row-tiles per barrier phase), raw barriers, guards for tails. ----------------

template<bool FIRST>
__global__ __launch_bounds__(512, 1) void k_megagru(const unsigned short* __restrict__ Z2all,
                                                    float* __restrict__ Hf,
                                                    const unsigned short* __restrict__ Wih,
                                                    const unsigned short* __restrict__ Whh,
                                                    const float* __restrict__ bfold,
                                                    const float* __restrict__ bhh, int rows, int NT) {
    __shared__ __align__(16) char hlds[2 * GRUROWS * 256];  // 32 KB h double-buffer
    __shared__ __align__(16) char wlds[384 * 256];          // 96 KB Whh, row-XOR swizzled
    const int HALF = GRUROWS * 256;                          // 16384 B
    int tid = threadIdx.x, w = tid >> 6, l = tid & 63, lr = l & 15, lk = l >> 4;
    int row0 = blockIdx.x * GRUROWS;
    int c = w * 16 + lr;

    // stage Whh -> LDS (coalesced global reads; swizzled writes)
    {
        const uint4* wsrc = (const uint4*)Whh;  // row = 128 bf16 = 16 chunks of 16B
        for (int i = tid; i < 384 * 16; i += 512) {
            int rw = i >> 4, chunk = i & 15;
            uint4 v = wsrc[(size_t)rw * 16 + chunk];
            int byte = rw * 256 + ((chunk * 16) ^ ((rw & 15) << 4));
            *(uint4*)(wlds + byte) = v;
        }
    }

    // Wih fragments (12 x 4 VGPR)
    bf8 Bi[3][4];
    const bf8* BiP = (const bf8*)Wih;
#pragma unroll
    for (int g = 0; g < 3; ++g)
#pragma unroll
        for (int ks = 0; ks < 4; ++ks)
            Bi[g][ks] = BiP[(size_t)(g * HIDDEN + c) * 16 + 4 * ks + lk];

    float bf_r = bfold[c], bf_z = bfold[HIDDEN + c], bf_n = bfold[2 * HIDDEN + c];
    float bh_n = bhh[2 * HIDDEN + c];

    float hreg[4][4];
    if (FIRST) {
#pragma unroll
        for (int m = 0; m < 4; ++m)
#pragma unroll
            for (int r = 0; r < 4; ++r) hreg[m][r] = 0.f;
        for (int i = tid; i < HALF / 4; i += 512) ((unsigned int*)hlds)[i] = 0u;
    } else {
#pragma unroll
        for (int m = 0; m < 4; ++m)
#pragma unroll
            for (int r = 0; r < 4; ++r) {
                int row = 16 * m + lk * 4 + r;
                int grow = row0 + row;
                float h = (grow < rows) ? Hf[(size_t)grow * HIDDEN + c] : 0.0f;
                hreg[m][r] = h;
                int byte = row * 256 + ((c * 2) ^ ((row & 15) << 4));
                *(unsigned short*)(hlds + byte) = f2bf(h);
            }
    }
    __syncthreads();  // init barrier: full drain once (covers wlds staging + h buffer 0)

    for (int t = 0; t < NT; ++t) {
        const int p = t & 1;
        const unsigned short* z2t = Z2all + ((size_t)t * rows + row0) * HIDDEN;

        // Whh fragments for this wave's 16-col slice: read ONCE per t, reused by all 4 m-tiles
        bf8 bwR[4], bwZ[4], bwN[4];
#pragma unroll
        for (int ks = 0; ks < 4; ++ks) {
            int wb = (ks * 64 + lk * 16) ^ (lr << 4);
            bwR[ks] = *(const bf8*)(wlds + (0 * HIDDEN + c) * 256 + wb);
            bwZ[ks] = *(const bf8*)(wlds + (1 * HIDDEN + c) * 256 + wb);
            bwN[ks] = *(const bf8*)(wlds + (2 * HIDDEN + c) * 256 + wb);
        }

#pragma unroll
        for (int m = 0; m < 4; ++m) {
            int rowA = row0 + 16 * m + lr;
            bool okA = rowA < rows;
            bf8 az[4];
            const bf8* zp = (const bf8*)(z2t + (size_t)(16 * m + lr) * HIDDEN);
#pragma unroll
            for (int ks = 0; ks < 4; ++ks)
                az[ks] = okA ? zp[4 * ks + lk] : (bf8){0, 0, 0, 0, 0, 0, 0, 0};
            bf8 ah[4];
#pragma unroll
            for (int ks = 0; ks < 4; ++ks) {
                int byte = p * HALF + (16 * m + lr) * 256 + ((ks * 64 + lk * 16) ^ (lr << 4));
                ah[ks] = *(const bf8*)(hlds + byte);
            }
            fx4 aR = (fx4){0.f, 0.f, 0.f, 0.f};
            fx4 aZ = (fx4){0.f, 0.f, 0.f, 0.f};
            fx4 aNi = (fx4){0.f, 0.f, 0.f, 0.f};
            fx4 aNh = (fx4){0.f, 0.f, 0.f, 0.f};
#pragma unroll
            for (int ks = 0; ks < 4; ++ks) {
                aR = __builtin_amdgcn_mfma_f32_16x16x32_bf16(ah[ks], bwR[ks], aR, 0, 0, 0);
                aZ = __builtin_amdgcn_mfma_f32_16x16x32_bf16(ah[ks], bwZ[ks], aZ, 0, 0, 0);
                aNh = __builtin_amdgcn_mfma_f32_16x16x32_bf16(ah[ks], bwN[ks], aNh, 0, 0, 0);
            }
#pragma unroll
            for (int ks = 0; ks < 4; ++ks) {
                aR = __builtin_amdgcn_mfma_f32_16x16x32_bf16(az[ks], Bi[0][ks], aR, 0, 0, 0);
                aZ = __builtin_amdgcn_mfma_f32_16x16x32_bf16(az[ks], Bi[1][ks], aZ, 0, 0, 0);
                aNi = __builtin_amdgcn_mfma_f32_16x16x32_bf16(az[ks], Bi[2][ks], aNi, 0, 0, 0);
            }
#pragma unroll
            for (int r = 0; r < 4; ++r) {
                int row = 16 * m + lk * 4 + r;
                float rr = sigm(aR[r] + bf_r);
                float zz = sigm(aZ[r] + bf_z);
                float nn = ftanh(aNi[r] + bf_n + rr * (aNh[r] + bh_n));
                float hnew = (1.0f - zz) * nn + zz * hreg[m][r];
                hreg[m][r] = hnew;
                int byte = (p ^ 1) * HALF + row * 256 + ((c * 2) ^ ((row & 15) << 4));
                *(unsigned short*)(hlds + byte) = f2bf(hnew);
            }
        }
        // LDS-only fence + barrier (no vmcnt drain)
        asm volatile("s_waitcnt lgkmcnt(0)" ::: "memory");
        __builtin_amdgcn_s_barrier();
        __builtin_amdgcn_sched_barrier(0);
    }

#pragma unroll
    for (int m = 0; m < 4; ++m)
#pragma unroll
        for (int r = 0; r < 4; ++r) {
            int grow = row0 + 16 * m + lk * 4 + r;
            if (grow < rows) Hf[(size_t)grow * HIDDEN + c] = hreg[m][r];
        }
}

// ---------------- output head: softmax(h @ W_out + b_out) ----------------

template<int NB>
__global__ __launch_bounds__(256) void k_out(const float* __restrict__ Hc, const float* __restrict__ Wo,
                                             const float* __restrict__ bo, float* __restrict__ out,
                                             int dayBase) {
    int rr = blockIdx.x * 4 + (threadIdx.x >> 6);
    if (rr >= N_NODES * NB) return;
    int lane = threadIdx.x & 63;
    float2 hv = ((const float2*)(Hc + (size_t)rr * HIDDEN))[lane];
    float l[5];
#pragma unroll
    for (int j = 0; j < 5; ++j) {
        float p = hv.x * Wo[(2 * lane) * 5 + j] + hv.y * Wo[(2 * lane + 1) * 5 + j];
#pragma unroll
        for (int s = 1; s < 64; s <<= 1) p += __shfl_xor(p, s);
        l[j] = p + bo[j];
    }
    float m = fmaxf(fmaxf(fmaxf(l[0], l[1]), fmaxf(l[2], l[3])), l[4]);
    float e0 = expf(l[0] - m), e1 = expf(l[1] - m), e2 = expf(l[2] - m), e3 = expf(l[3] - m), e4 = expf(l[4] - m);
    float inv = 1.0f / (e0 + e1 + e2 + e3 + e4);
    if (lane < 5) {
        float ej = lane == 0 ? e0 : lane == 1 ? e1 : lane == 2 ? e2 : lane == 3 ? e3 : e4;
        int n = rr / NB, dd = dayBase + rr % NB;
        out[((size_t)dd * N_NODES + n) * 5 + lane] = ej * inv;
    }
}

// ---------------- per-tier pipeline: stage nt timesteps per launch-pair, megagru per 4/3-group ----------------

template<int NB>
static void run_tier(const float* x, const float* W1, const float* b1,
                     const unsigned short* W2T_bf, const float* b2,
                     const unsigned short* Wih_bf, const unsigned short* Whh_bf,
                     const float* b_fold, const float* b_hh,
                     const float* W_out, const float* b_out, float* out,
                     const int* row_start, const int* csr_src, const float* csr_norm,
                     const float* self_norm,
                     float* xa, unsigned short* H2all, unsigned short* Z2all, float* Hf,
                     int slots, hipStream_t stream) {
    const int rows = N_NODES * NB;
    const unsigned ngrid = (N_NODES + 3) / 4;
    const unsigned gblk = (unsigned)((rows + 63) / 64);
    const unsigned gru_grid = (unsigned)((rows + GRUROWS - 1) / GRUROWS);
    const int rounds = NDAYS / NB;

    auto stage = [&](int t0, int nt, int zbase) {
        dim3 gz(gblk, (unsigned)nt);
        k_z1gemm<<<gz, 256, 0, stream>>>(xa, W1, b1, W2T_bf, H2all, rows, t0);
        dim3 ga(ngrid, (unsigned)nt);
        k_agg<NB><<<ga, 256, 0, stream>>>((const uint4*)H2all,
                                          (uint4*)(Z2all + (size_t)(t0 - zbase) * rows * HIDDEN), b2,
                                          row_start, csr_src, csr_norm, self_norm, rows);
    };

    for (int dd = 0; dd < rounds; ++dd) {
        int dayBase = dd * NB;
        k_aggx<NB><<<ngrid, 256, 0, stream>>>(x, xa, row_start, csr_src, csr_norm, self_norm, dayBase);
        // group 1: t = 0..3
        for (int t0 = 0; t0 < 4; t0 += slots) stage(t0, (4 - t0 < slots) ? (4 - t0) : slots, 0);
        k_megagru<true><<<gru_grid, 512, 0, stream>>>(Z2all, Hf, Wih_bf, Whh_bf, b_fold, b_hh, rows, 4);
        // group 2: t = 4..6
        for (int t0 = 4; t0 < LOOKBACK; t0 += slots)
            stage(t0, (LOOKBACK - t0 < slots) ? (LOOKBACK - t0) : slots, 4);
        k_megagru<false><<<gru_grid, 512, 0, stream>>>(Z2all, Hf, Wih_bf, Whh_bf, b_fold, b_hh, rows, 3);
        k_out<NB><<<(unsigned)((rows + 3) / 4), 256, 0, stream>>>(Hf, W_out, b_out, out, dayBase);
    }
}

// ---------------- launch ----------------

extern "C" void kernel_launch(void* const* d_in, const int* in_sizes, int n_in,
                              void* d_out, int out_size, void* d_ws, size_t ws_size,
                              hipStream_t stream) {
    const float* x     = (const float*)d_in[0];
    const int*   ei    = (const int*)d_in[1];
    const float* W1    = (const float*)d_in[2];
    const float* b1    = (const float*)d_in[3];
    const float* W2    = (const float*)d_in[4];
    const float* b2    = (const float*)d_in[5];
    const float* W_ih  = (const float*)d_in[6];
    const float* W_hh  = (const float*)d_in[7];
    const float* b_ih  = (const float*)d_in[8];
    const float* b_hh  = (const float*)d_in[9];
    const float* W_out = (const float*)d_in[10];
    const float* b_out = (const float*)d_in[11];
    float* out = (float*)d_out;

    size_t off = 0;
    char* wsb = (char*)d_ws;
    auto alloc = [&](size_t bytes) -> void* {
        void* p = wsb + off;
        off = (off + bytes + 255) & ~(size_t)255;
        return p;
    };
    int*            deg       = (int*)alloc(N_NODES * 4);
    int*            cursor    = (int*)alloc(N_NODES * 4);
    int*            row_start = (int*)alloc((N_NODES + 1) * 4);
    float*          dinv      = (float*)alloc(N_NODES * 4);
    float*          self_norm = (float*)alloc(N_NODES * 4);
    unsigned short* W2T_bf    = (unsigned short*)alloc(HIDDEN * HIDDEN * 2);
    unsigned short* Wih_bf    = (unsigned short*)alloc(3 * HIDDEN * HIDDEN * 2);
    unsigned short* Whh_bf    = (unsigned short*)alloc(3 * HIDDEN * HIDDEN * 2);
    float*          b_fold    = (float*)alloc(3 * HIDDEN * 4);
    int*            csr_src   = (int*)alloc(N_EDGES * 4);
    float*          csr_norm  = (float*)alloc(N_EDGES * 4);

    // per-row bytes: xa 140 + H2all slots*256 + Z2all 4*256 + Hf 512
    size_t prep_off = off;
    auto need = [&](int nb, int slots) -> size_t {
        return prep_off + (size_t)N_NODES * nb * (140 + (size_t)slots * 256 + 1024 + 512) + 16384;
    };
    int NBsel, slots;
    if (need(4, 2) <= ws_size)      { NBsel = 4; slots = 2; }
    else if (need(4, 1) <= ws_size) { NBsel = 4; slots = 1; }
    else if (need(2, 2) <= ws_size) { NBsel = 2; slots = 2; }
    else if (need(2, 1) <= ws_size) { NBsel = 2; slots = 1; }
    else                            { NBsel = 1; slots = 1; }
    int rows = N_NODES * NBsel;

    float*          xa    = (float*)alloc((size_t)rows * XROW * 4);
    unsigned short* H2all = (unsigned short*)alloc((size_t)slots * rows * HIDDEN * 2);
    unsigned short* Z2all = (unsigned short*)alloc((size_t)4 * rows * HIDDEN * 2);
    float*          Hf    = (float*)alloc((size_t)rows * HIDDEN * 4);

    // graph + weight prep
    hipMemsetAsync(deg, 0, N_NODES * 4, stream);
    hipMemsetAsync(cursor, 0, N_NODES * 4, stream);
    k_deg<<<(N_EDGES + 255) / 256, 256, 0, stream>>>(ei, deg);
    k_scan<<<1, 1024, 0, stream>>>(deg, row_start);
    k_dinv<<<(N_NODES + 255) / 256, 256, 0, stream>>>(deg, dinv, self_norm);
    k_fill<<<(N_EDGES + 255) / 256, 256, 0, stream>>>(ei, row_start, cursor, dinv, csr_src, csr_norm);
    k_w2t<<<(HIDDEN * HIDDEN + 255) / 256, 256, 0, stream>>>(W2, W2T_bf);
    k_cast<<<(3 * HIDDEN * HIDDEN + 255) / 256, 256, 0, stream>>>(W_ih, Wih_bf, 3 * HIDDEN * HIDDEN);
    k_cast<<<(3 * HIDDEN * HIDDEN + 255) / 256, 256, 0, stream>>>(W_hh, Whh_bf, 3 * HIDDEN * HIDDEN);
    k_bfold<<<2, 256, 0, stream>>>(b_ih, b_hh, b_fold);

    if (NBsel == 4)
        run_tier<4>(x, W1, b1, W2T_bf, b2, Wih_bf, Whh_bf, b_fold, b_hh, W_out, b_out, out,
                    row_start, csr_src, csr_norm, self_norm, xa, H2all, Z2all, Hf, slots, stream);
    else if (NBsel == 2)
        run_tier<2>(x, W1, b1, W2T_bf, b2, Wih_bf, Whh_bf, b_fold, b_hh, W_out, b_out, out,
                    row_start, csr_src, csr_norm, self_norm, xa, H2all, Z2all, Hf, slots, stream);
    else
        run_tier<1>(x, W1, b1, W2T_bf, b2, Wih_bf, Whh_bf, b_fold, b_hh, W_out, b_out, out,
                    row_start, csr_src, csr_norm, self_norm, xa, H2all, Z2all, Hf, slots, stream);
}

// Round 19
// 935.209 us; speedup vs baseline: 1.6039x; 1.0264x over previous
//
#include <hip/hip_runtime.h>
#include <cstddef>
#include <cstdint>

#define N_NODES 20000
#define N_EDGES 320000
#define NDAYS 4
#define LOOKBACK 7
#define NFEAT 5
#define XROW (LOOKBACK * NFEAT)  // 35
#define HIDDEN 128
#define GRUROWS 64  // rows per k_megagru block (4 tiles of 16); guards handle non-multiple tails

typedef short bf8 __attribute__((ext_vector_type(8)));
typedef float fx4 __attribute__((ext_vector_type(4)));

__device__ __forceinline__ float bflo(unsigned int u) {
    union { unsigned int u; float f; } v; v.u = u << 16; return v.f;
}
__device__ __forceinline__ float bfhi(unsigned int u) {
    union { unsigned int u; float f; } v; v.u = u & 0xffff0000u; return v.f;
}
__device__ __forceinline__ unsigned short f2bf(float f) {
    union { float f; unsigned int u; } v; v.f = f;
    unsigned int u = v.u + 0x7fffu + ((v.u >> 16) & 1u);
    return (unsigned short)(u >> 16);
}
__device__ __forceinline__ unsigned int packbf(float a, float b) {
    return (unsigned int)f2bf(a) | ((unsigned int)f2bf(b) << 16);
}
__device__ __forceinline__ float sigm(float v) { return 1.0f / (1.0f + __expf(-v)); }
__device__ __forceinline__ float ftanh(float v) {
    float e2 = __expf(2.0f * v);
    return (e2 - 1.0f) / (e2 + 1.0f);
}
__device__ __forceinline__ void accum8(float* a, uint4 v, float w) {
    a[0] += w * bflo(v.x); a[1] += w * bfhi(v.x);
    a[2] += w * bflo(v.y); a[3] += w * bfhi(v.y);
    a[4] += w * bflo(v.z); a[5] += w * bfhi(v.z);
    a[6] += w * bflo(v.w); a[7] += w * bfhi(v.w);
}

// ---------------- graph preprocessing ----------------

__global__ __launch_bounds__(256) void k_deg(const int* __restrict__ ei, int* __restrict__ deg) {
    int e = blockIdx.x * 256 + threadIdx.x;
    if (e < N_EDGES) atomicAdd(&deg[ei[N_EDGES + e]], 1);
}

__global__ __launch_bounds__(1024) void k_scan(const int* __restrict__ deg, int* __restrict__ row_start) {
    __shared__ int part[1024];
    int tid = threadIdx.x;
    const int chunk = (N_NODES + 1023) / 1024;  // 20
    int i0 = tid * chunk;
    int i1 = min(i0 + chunk, N_NODES);
    int s = 0;
    for (int i = i0; i < i1; ++i) s += deg[i];
    part[tid] = s;
    __syncthreads();
    for (int d = 1; d < 1024; d <<= 1) {
        int v = (tid >= d) ? part[tid - d] : 0;
        __syncthreads();
        part[tid] += v;
        __syncthreads();
    }
    int base = part[tid] - s;  // exclusive prefix
    for (int i = i0; i < i1; ++i) { row_start[i] = base; base += deg[i]; }
    if (tid == 1023) row_start[N_NODES] = part[1023];
}

__global__ __launch_bounds__(256) void k_dinv(const int* __restrict__ deg, float* __restrict__ dinv,
                                              float* __restrict__ self_norm) {
    int i = blockIdx.x * 256 + threadIdx.x;
    if (i >= N_NODES) return;
    float d = (float)(deg[i] + 1);
    dinv[i] = 1.0f / sqrtf(d);
    self_norm[i] = 1.0f / d;
}

__global__ __launch_bounds__(256) void k_fill(const int* __restrict__ ei, const int* __restrict__ row_start,
                                              int* __restrict__ cursor, const float* __restrict__ dinv,
                                              int* __restrict__ csr_src, float* __restrict__ csr_norm) {
    int e = blockIdx.x * 256 + threadIdx.x;
    if (e >= N_EDGES) return;
    int s = ei[e], d = ei[N_EDGES + e];
    int pos = row_start[d] + atomicAdd(&cursor[d], 1);
    csr_src[pos] = s;
    csr_norm[pos] = dinv[s] * dinv[d];
}

// W2T_bf[c][k] = bf16(W2[k][c])
__global__ __launch_bounds__(256) void k_w2t(const float* __restrict__ W2, unsigned short* __restrict__ W2T) {
    int idx = blockIdx.x * 256 + threadIdx.x;
    if (idx >= HIDDEN * HIDDEN) return;
    int k = idx >> 7, c = idx & 127;
    W2T[c * HIDDEN + k] = f2bf(W2[k * HIDDEN + c]);
}

__global__ __launch_bounds__(256) void k_cast(const float* __restrict__ src, unsigned short* __restrict__ dst, int n) {
    int i = blockIdx.x * 256 + threadIdx.x;
    if (i < n) dst[i] = f2bf(src[i]);
}

// b_fold[j] = b_ih[j] + b_hh[j] for r,z gates (j<256); b_ih[j] only for n gate
__global__ __launch_bounds__(256) void k_bfold(const float* __restrict__ b_ih, const float* __restrict__ b_hh,
                                               float* __restrict__ b_fold) {
    int i = blockIdx.x * 256 + threadIdx.x;
    if (i < 3 * HIDDEN) b_fold[i] = b_ih[i] + (i < 2 * HIDDEN ? b_hh[i] : 0.0f);
}

// ---------------- feature-space aggregation: xa[node*NB+b] = agg(x)[day b] ----------------

template<int NB>
__global__ __launch_bounds__(256) void k_aggx(const float* __restrict__ x, float* __restrict__ xa,
                                              const int* __restrict__ row_start, const int* __restrict__ csr_src,
                                              const float* __restrict__ csr_norm,
                                              const float* __restrict__ self_norm, int dayBase) {
    int n = blockIdx.x * 4 + (threadIdx.x >> 6);
    if (n >= N_NODES) return;
    int lane = threadIdx.x & 63;
    if (lane >= XROW) return;
    float sn = self_norm[n];
    float acc[NB];
#pragma unroll
    for (int b = 0; b < NB; ++b)
        acc[b] = x[(size_t)((dayBase + b) * N_NODES + n) * XROW + lane] * sn;
    int e1 = row_start[n + 1];
    for (int e = row_start[n]; e < e1; ++e) {
        int s = csr_src[e];
        float w = csr_norm[e];
#pragma unroll
        for (int b = 0; b < NB; ++b)
            acc[b] += w * x[(size_t)((dayBase + b) * N_NODES + s) * XROW + lane];
    }
#pragma unroll
    for (int b = 0; b < NB; ++b)
        xa[(size_t)(n * NB + b) * XROW + lane] = acc[b];
}

// ---------------- fused Z1+GEMM (t-batched via blockIdx.y): H2all[y] = relu(xa_{t0+y} @ W1 + b1) @ W2 ----------------

__global__ __launch_bounds__(256) void k_z1gemm(const float* __restrict__ xa, const float* __restrict__ W1,
                                                const float* __restrict__ b1,
                                                const unsigned short* __restrict__ W2T,
                                                unsigned short* __restrict__ H2all, int rows, int t0) {
    int tid = threadIdx.x, w = tid >> 6, l = tid & 63, lr = l & 15, lk = l >> 4;
    int t = t0 + blockIdx.y;
    unsigned short* H2 = H2all + (size_t)blockIdx.y * rows * HIDDEN;
    int rblk = blockIdx.x * 64;
    int rowA = rblk + w * 16 + lr;
    bool okA = rowA < rows;
    float x5[5];
#pragma unroll
    for (int k = 0; k < 5; ++k)
        x5[k] = okA ? xa[(size_t)rowA * XROW + t * NFEAT + k] : 0.0f;
    bf8 az[4];
#pragma unroll
    for (int ks = 0; ks < 4; ++ks) {
#pragma unroll
        for (int j = 0; j < 8; ++j) {
            int ch = 32 * ks + 8 * lk + j;
            float v = b1[ch] + x5[0] * W1[ch] + x5[1] * W1[128 + ch] + x5[2] * W1[256 + ch]
                    + x5[3] * W1[384 + ch] + x5[4] * W1[512 + ch];
            az[ks][j] = (short)f2bf(fmaxf(v, 0.0f));
        }
    }
    const bf8* Bp = (const bf8*)W2T;
    fx4 acc[8];
#pragma unroll
    for (int n = 0; n < 8; ++n) acc[n] = (fx4){0.f, 0.f, 0.f, 0.f};
#pragma unroll
    for (int ks = 0; ks < 4; ++ks) {
#pragma unroll
        for (int n = 0; n < 8; ++n) {
            bf8 b = Bp[(size_t)(16 * n + lr) * 16 + 4 * ks + lk];
            acc[n] = __builtin_amdgcn_mfma_f32_16x16x32_bf16(az[ks], b, acc[n], 0, 0, 0);
        }
    }
#pragma unroll
    for (int n = 0; n < 8; ++n)
#pragma unroll
        for (int r = 0; r < 4; ++r) {
            int row = rblk + w * 16 + lk * 4 + r;
            if (row < rows) H2[(size_t)row * HIDDEN + 16 * n + lr] = f2bf(acc[n][r]);
        }
}

// ---------------- hidden-space aggregation (t-batched via blockIdx.y), day-interleaved layout ----------------
// One wave per node; edge loop unrolled x8 (8KB in flight per wave) to cover L2/fabric latency.

template<int NB>
__global__ __launch_bounds__(256) void k_agg(const uint4* __restrict__ H2all, uint4* __restrict__ Zall,
                                             const float* __restrict__ bias,
                                             const int* __restrict__ row_start, const int* __restrict__ csr_src,
                                             const float* __restrict__ csr_norm,
                                             const float* __restrict__ self_norm, int rows) {
    int n = blockIdx.x * 4 + (threadIdx.x >> 6);
    if (n >= N_NODES) return;
    int l = threadIdx.x & 63;
    if (l >= NB * 16) return;
    const uint4* H = H2all + (size_t)blockIdx.y * rows * 16;
    uint4* Z = Zall + (size_t)blockIdx.y * rows * 16;
    int c0 = (l & 15) * 8;
    float sn = self_norm[n];
    float a[8];
    {
        uint4 sv = H[(size_t)n * (NB * 16) + l];
        a[0] = bflo(sv.x) * sn; a[1] = bfhi(sv.x) * sn;
        a[2] = bflo(sv.y) * sn; a[3] = bfhi(sv.y) * sn;
        a[4] = bflo(sv.z) * sn; a[5] = bfhi(sv.z) * sn;
        a[6] = bflo(sv.w) * sn; a[7] = bfhi(sv.w) * sn;
    }
    int e1 = row_start[n + 1];
    int e = row_start[n];
    for (; e + 7 < e1; e += 8) {
        int s0 = csr_src[e],     s1 = csr_src[e + 1], s2 = csr_src[e + 2], s3 = csr_src[e + 3];
        int s4 = csr_src[e + 4], s5 = csr_src[e + 5], s6 = csr_src[e + 6], s7 = csr_src[e + 7];
        float w0 = csr_norm[e],     w1 = csr_norm[e + 1], w2 = csr_norm[e + 2], w3 = csr_norm[e + 3];
        float w4 = csr_norm[e + 4], w5 = csr_norm[e + 5], w6 = csr_norm[e + 6], w7 = csr_norm[e + 7];
        uint4 v0 = H[(size_t)s0 * (NB * 16) + l];
        uint4 v1 = H[(size_t)s1 * (NB * 16) + l];
        uint4 v2 = H[(size_t)s2 * (NB * 16) + l];
        uint4 v3 = H[(size_t)s3 * (NB * 16) + l];
        uint4 v4 = H[(size_t)s4 * (NB * 16) + l];
        uint4 v5 = H[(size_t)s5 * (NB * 16) + l];
        uint4 v6 = H[(size_t)s6 * (NB * 16) + l];
        uint4 v7 = H[(size_t)s7 * (NB * 16) + l];
        accum8(a, v0, w0); accum8(a, v1, w1); accum8(a, v2, w2); accum8(a, v3, w3);
        accum8(a, v4, w4); accum8(a, v5, w5); accum8(a, v6, w6); accum8(a, v7, w7);
    }
    for (; e + 3 < e1; e += 4) {
        int s0 = csr_src[e], s1 = csr_src[e + 1], s2 = csr_src[e + 2], s3 = csr_src[e + 3];
        float w0 = csr_norm[e], w1 = csr_norm[e + 1], w2 = csr_norm[e + 2], w3 = csr_norm[e + 3];
        uint4 v0 = H[(size_t)s0 * (NB * 16) + l];
        uint4 v1 = H[(size_t)s1 * (NB * 16) + l];
        uint4 v2 = H[(size_t)s2 * (NB * 16) + l];
        uint4 v3 = H[(size_t)s3 * (NB * 16) + l];
        accum8(a, v0, w0); accum8(a, v1, w1); accum8(a, v2, w2); accum8(a, v3, w3);
    }
    for (; e < e1; ++e) {
        int s = csr_src[e];
        float w = csr_norm[e];
        uint4 v = H[(size_t)s * (NB * 16) + l];
        accum8(a, v, w);
    }
    const float* bp = bias + c0;
    uint4 o;
    o.x = packbf(fmaxf(a[0] + bp[0], 0.f), fmaxf(a[1] + bp[1], 0.f));
    o.y = packbf(fmaxf(a[2] + bp[2], 0.f), fmaxf(a[3] + bp[3], 0.f));
    o.z = packbf(fmaxf(a[4] + bp[4], 0.f), fmaxf(a[5] + bp[5], 0.f));
    o.w = packbf(fmaxf(a[6] + bp[6], 0.f), fmaxf(a[7] + bp[7], 0.f));
    Z[(size_t)n * (NB * 16) + l] = o;
}

// ---------------- mega GRU (R14 v6, measured best): Whh in swizzled LDS read once per t,
// GRUROWS=64 (4 row-tiles per barrier phase), raw barriers, guards for tails. ----------------

template<bool FIRST>
__global__ __launch_bounds__(512, 1) void k_megagru(const unsigned short* __restrict__ Z2all,
                                                    float* __restrict__ Hf,
                                                    const unsigned short* __restrict__ Wih,
                                                    const unsigned short* __restrict__ Whh,
                                                    const float* __restrict__ bfold,
                                                    const float* __restrict__ bhh, int rows, int NT) {
    __shared__ __align__(16) char hlds[2 * GRUROWS * 256];  // 32 KB h double-buffer
    __shared__ __align__(16) char wlds[384 * 256];          // 96 KB Whh, row-XOR swizzled
    const int HALF = GRUROWS * 256;                          // 16384 B
    int tid = threadIdx.x, w = tid >> 6, l = tid & 63, lr = l & 15, lk = l >> 4;
    int row0 = blockIdx.x * GRUROWS;
    int c = w * 16 + lr;

    // stage Whh -> LDS (coalesced global reads; swizzled writes)
    {
        const uint4* wsrc = (const uint4*)Whh;  // row = 128 bf16 = 16 chunks of 16B
        for (int i = tid; i < 384 * 16; i += 512) {
            int rw = i >> 4, chunk = i & 15;
            uint4 v = wsrc[(size_t)rw * 16 + chunk];
            int byte = rw * 256 + ((chunk * 16) ^ ((rw & 15) << 4));
            *(uint4*)(wlds + byte) = v;
        }
    }

    // Wih fragments (12 x 4 VGPR)
    bf8 Bi[3][4];
    const bf8* BiP = (const bf8*)Wih;
#pragma unroll
    for (int g = 0; g < 3; ++g)
#pragma unroll
        for (int ks = 0; ks < 4; ++ks)
            Bi[g][ks] = BiP[(size_t)(g * HIDDEN + c) * 16 + 4 * ks + lk];

    float bf_r = bfold[c], bf_z = bfold[HIDDEN + c], bf_n = bfold[2 * HIDDEN + c];
    float bh_n = bhh[2 * HIDDEN + c];

    float hreg[4][4];
    if (FIRST) {
#pragma unroll
        for (int m = 0; m < 4; ++m)
#pragma unroll
            for (int r = 0; r < 4; ++r) hreg[m][r] = 0.f;
        for (int i = tid; i < HALF / 4; i += 512) ((unsigned int*)hlds)[i] = 0u;
    } else {
#pragma unroll
        for (int m = 0; m < 4; ++m)
#pragma unroll
            for (int r = 0; r < 4; ++r) {
                int row = 16 * m + lk * 4 + r;
                int grow = row0 + row;
                float h = (grow < rows) ? Hf[(size_t)grow * HIDDEN + c] : 0.0f;
                hreg[m][r] = h;
                int byte = row * 256 + ((c * 2) ^ ((row & 15) << 4));
                *(unsigned short*)(hlds + byte) = f2bf(h);
            }
    }
    __syncthreads();  // init barrier: full drain once (covers wlds staging + h buffer 0)

    for (int t = 0; t < NT; ++t) {
        const int p = t & 1;
        const unsigned short* z2t = Z2all + ((size_t)t * rows + row0) * HIDDEN;

        // Whh fragments for this wave's 16-col slice: read ONCE per t, reused by all 4 m-tiles
        bf8 bwR[4], bwZ[4], bwN[4];
#pragma unroll
        for (int ks = 0; ks < 4; ++ks) {
            int wb = (ks * 64 + lk * 16) ^ (lr << 4);
            bwR[ks] = *(const bf8*)(wlds + (0 * HIDDEN + c) * 256 + wb);
            bwZ[ks] = *(const bf8*)(wlds + (1 * HIDDEN + c) * 256 + wb);
            bwN[ks] = *(const bf8*)(wlds + (2 * HIDDEN + c) * 256 + wb);
        }

#pragma unroll
        for (int m = 0; m < 4; ++m) {
            int rowA = row0 + 16 * m + lr;
            bool okA = rowA < rows;
            bf8 az[4];
            const bf8* zp = (const bf8*)(z2t + (size_t)(16 * m + lr) * HIDDEN);
#pragma unroll
            for (int ks = 0; ks < 4; ++ks)
                az[ks] = okA ? zp[4 * ks + lk] : (bf8){0, 0, 0, 0, 0, 0, 0, 0};
            bf8 ah[4];
#pragma unroll
            for (int ks = 0; ks < 4; ++ks) {
                int byte = p * HALF + (16 * m + lr) * 256 + ((ks * 64 + lk * 16) ^ (lr << 4));
                ah[ks] = *(const bf8*)(hlds + byte);
            }
            fx4 aR = (fx4){0.f, 0.f, 0.f, 0.f};
            fx4 aZ = (fx4){0.f, 0.f, 0.f, 0.f};
            fx4 aNi = (fx4){0.f, 0.f, 0.f, 0.f};
            fx4 aNh = (fx4){0.f, 0.f, 0.f, 0.f};
#pragma unroll
            for (int ks = 0; ks < 4; ++ks) {
                aR = __builtin_amdgcn_mfma_f32_16x16x32_bf16(ah[ks], bwR[ks], aR, 0, 0, 0);
                aZ = __builtin_amdgcn_mfma_f32_16x16x32_bf16(ah[ks], bwZ[ks], aZ, 0, 0, 0);
                aNh = __builtin_amdgcn_mfma_f32_16x16x32_bf16(ah[ks], bwN[ks], aNh, 0, 0, 0);
            }
#pragma unroll
            for (int ks = 0; ks < 4; ++ks) {
                aR = __builtin_amdgcn_mfma_f32_16x16x32_bf16(az[ks], Bi[0][ks], aR, 0, 0, 0);
                aZ = __builtin_amdgcn_mfma_f32_16x16x32_bf16(az[ks], Bi[1][ks], aZ, 0, 0, 0);
                aNi = __builtin_amdgcn_mfma_f32_16x16x32_bf16(az[ks], Bi[2][ks], aNi, 0, 0, 0);
            }
#pragma unroll
            for (int r = 0; r < 4; ++r) {
                int row = 16 * m + lk * 4 + r;
                float rr = sigm(aR[r] + bf_r);
                float zz = sigm(aZ[r] + bf_z);
                float nn = ftanh(aNi[r] + bf_n + rr * (aNh[r] + bh_n));
                float hnew = (1.0f - zz) * nn + zz * hreg[m][r];
                hreg[m][r] = hnew;
                int byte = (p ^ 1) * HALF + row * 256 + ((c * 2) ^ ((row & 15) << 4));
                *(unsigned short*)(hlds + byte) = f2bf(hnew);
            }
        }
        // LDS-only fence + barrier (no vmcnt drain)
        asm volatile("s_waitcnt lgkmcnt(0)" ::: "memory");
        __builtin_amdgcn_s_barrier();
        __builtin_amdgcn_sched_barrier(0);
    }

#pragma unroll
    for (int m = 0; m < 4; ++m)
#pragma unroll
        for (int r = 0; r < 4; ++r) {
            int grow = row0 + 16 * m + lk * 4 + r;
            if (grow < rows) Hf[(size_t)grow * HIDDEN + c] = hreg[m][r];
        }
}

// ---------------- output head: softmax(h @ W_out + b_out) ----------------

template<int NB>
__global__ __launch_bounds__(256) void k_out(const float* __restrict__ Hc, const float* __restrict__ Wo,
                                             const float* __restrict__ bo, float* __restrict__ out,
                                             int dayBase) {
    int rr = blockIdx.x * 4 + (threadIdx.x >> 6);
    if (rr >= N_NODES * NB) return;
    int lane = threadIdx.x & 63;
    float2 hv = ((const float2*)(Hc + (size_t)rr * HIDDEN))[lane];
    float l[5];
#pragma unroll
    for (int j = 0; j < 5; ++j) {
        float p = hv.x * Wo[(2 * lane) * 5 + j] + hv.y * Wo[(2 * lane + 1) * 5 + j];
#pragma unroll
        for (int s = 1; s < 64; s <<= 1) p += __shfl_xor(p, s);
        l[j] = p + bo[j];
    }
    float m = fmaxf(fmaxf(fmaxf(l[0], l[1]), fmaxf(l[2], l[3])), l[4]);
    float e0 = expf(l[0] - m), e1 = expf(l[1] - m), e2 = expf(l[2] - m), e3 = expf(l[3] - m), e4 = expf(l[4] - m);
    float inv = 1.0f / (e0 + e1 + e2 + e3 + e4);
    if (lane < 5) {
        float ej = lane == 0 ? e0 : lane == 1 ? e1 : lane == 2 ? e2 : lane == 3 ? e3 : e4;
        int n = rr / NB, dd = dayBase + rr % NB;
        out[((size_t)dd * N_NODES + n) * 5 + lane] = ej * inv;
    }
}

// ---------------- per-tier pipeline: stage nt timesteps per launch-pair, megagru per 4/3-group ----------------

template<int NB>
static void run_tier(const float* x, const float* W1, const float* b1,
                     const unsigned short* W2T_bf, const float* b2,
                     const unsigned short* Wih_bf, const unsigned short* Whh_bf,
                     const float* b_fold, const float* b_hh,
                     const float* W_out, const float* b_out, float* out,
                     const int* row_start, const int* csr_src, const float* csr_norm,
                     const float* self_norm,
                     float* xa, unsigned short* H2all, unsigned short* Z2all, float* Hf,
                     int slots, hipStream_t stream) {
    const int rows = N_NODES * NB;
    const unsigned ngrid = (N_NODES + 3) / 4;
    const unsigned gblk = (unsigned)((rows + 63) / 64);
    const unsigned gru_grid = (unsigned)((rows + GRUROWS - 1) / GRUROWS);
    const int rounds = NDAYS / NB;

    auto stage = [&](int t0, int nt, int zbase) {
        dim3 gz(gblk, (unsigned)nt);
        k_z1gemm<<<gz, 256, 0, stream>>>(xa, W1, b1, W2T_bf, H2all, rows, t0);
        dim3 ga(ngrid, (unsigned)nt);
        k_agg<NB><<<ga, 256, 0, stream>>>((const uint4*)H2all,
                                          (uint4*)(Z2all + (size_t)(t0 - zbase) * rows * HIDDEN), b2,
                                          row_start, csr_src, csr_norm, self_norm, rows);
    };

    for (int dd = 0; dd < rounds; ++dd) {
        int dayBase = dd * NB;
        k_aggx<NB><<<ngrid, 256, 0, stream>>>(x, xa, row_start, csr_src, csr_norm, self_norm, dayBase);
        // group 1: t = 0..3
        for (int t0 = 0; t0 < 4; t0 += slots) stage(t0, (4 - t0 < slots) ? (4 - t0) : slots, 0);
        k_megagru<true><<<gru_grid, 512, 0, stream>>>(Z2all, Hf, Wih_bf, Whh_bf, b_fold, b_hh, rows, 4);
        // group 2: t = 4..6
        for (int t0 = 4; t0 < LOOKBACK; t0 += slots)
            stage(t0, (LOOKBACK - t0 < slots) ? (LOOKBACK - t0) : slots, 4);
        k_megagru<false><<<gru_grid, 512, 0, stream>>>(Z2all, Hf, Wih_bf, Whh_bf, b_fold, b_hh, rows, 3);
        k_out<NB><<<(unsigned)((rows + 3) / 4), 256, 0, stream>>>(Hf, W_out, b_out, out, dayBase);
    }
}

// ---------------- launch ----------------

extern "C" void kernel_launch(void* const* d_in, const int* in_sizes, int n_in,
                              void* d_out, int out_size, void* d_ws, size_t ws_size,
                              hipStream_t stream) {
    const float* x     = (const float*)d_in[0];
    const int*   ei    = (const int*)d_in[1];
    const float* W1    = (const float*)d_in[2];
    const float* b1    = (const float*)d_in[3];
    const float* W2    = (const float*)d_in[4];
    const float* b2    = (const float*)d_in[5];
    const float* W_ih  = (const float*)d_in[6];
    const float* W_hh  = (const float*)d_in[7];
    const float* b_ih  = (const float*)d_in[8];
    const float* b_hh  = (const float*)d_in[9];
    const float* W_out = (const float*)d_in[10];
    const float* b_out = (const float*)d_in[11];
    float* out = (float*)d_out;

    size_t off = 0;
    char* wsb = (char*)d_ws;
    auto alloc = [&](size_t bytes) -> void* {
        void* p = wsb + off;
        off = (off + bytes + 255) & ~(size_t)255;
        return p;
    };
    int*            deg       = (int*)alloc(N_NODES * 4);
    int*            cursor    = (int*)alloc(N_NODES * 4);
    int*            row_start = (int*)alloc((N_NODES + 1) * 4);
    float*          dinv      = (float*)alloc(N_NODES * 4);
    float*          self_norm = (float*)alloc(N_NODES * 4);
    unsigned short* W2T_bf    = (unsigned short*)alloc(HIDDEN * HIDDEN * 2);
    unsigned short* Wih_bf    = (unsigned short*)alloc(3 * HIDDEN * HIDDEN * 2);
    unsigned short* Whh_bf    = (unsigned short*)alloc(3 * HIDDEN * HIDDEN * 2);
    float*          b_fold    = (float*)alloc(3 * HIDDEN * 4);
    int*            csr_src   = (int*)alloc(N_EDGES * 4);
    float*          csr_norm  = (float*)alloc(N_EDGES * 4);

    // per-row bytes: xa 140 + H2all slots*256 + Z2all 4*256 + Hf 512
    size_t prep_off = off;
    auto need = [&](int nb, int slots) -> size_t {
        return prep_off + (size_t)N_NODES * nb * (140 + (size_t)slots * 256 + 1024 + 512) + 16384;
    };
    int NBsel, slots;
    if (need(4, 4) <= ws_size)      { NBsel = 4; slots = 4; }
    else if (need(4, 3) <= ws_size) { NBsel = 4; slots = 3; }
    else if (need(4, 2) <= ws_size) { NBsel = 4; slots = 2; }
    else if (need(4, 1) <= ws_size) { NBsel = 4; slots = 1; }
    else if (need(2, 2) <= ws_size) { NBsel = 2; slots = 2; }
    else if (need(2, 1) <= ws_size) { NBsel = 2; slots = 1; }
    else                            { NBsel = 1; slots = 1; }
    int rows = N_NODES * NBsel;

    float*          xa    = (float*)alloc((size_t)rows * XROW * 4);
    unsigned short* H2all = (unsigned short*)alloc((size_t)slots * rows * HIDDEN * 2);
    unsigned short* Z2all = (unsigned short*)alloc((size_t)4 * rows * HIDDEN * 2);
    float*          Hf    = (float*)alloc((size_t)rows * HIDDEN * 4);

    // graph + weight prep
    hipMemsetAsync(deg, 0, N_NODES * 4, stream);
    hipMemsetAsync(cursor, 0, N_NODES * 4, stream);
    k_deg<<<(N_EDGES + 255) / 256, 256, 0, stream>>>(ei, deg);
    k_scan<<<1, 1024, 0, stream>>>(deg, row_start);
    k_dinv<<<(N_NODES + 255) / 256, 256, 0, stream>>>(deg, dinv, self_norm);
    k_fill<<<(N_EDGES + 255) / 256, 256, 0, stream>>>(ei, row_start, cursor, dinv, csr_src, csr_norm);
    k_w2t<<<(HIDDEN * HIDDEN + 255) / 256, 256, 0, stream>>>(W2, W2T_bf);
    k_cast<<<(3 * HIDDEN * HIDDEN + 255) / 256, 256, 0, stream>>>(W_ih, Wih_bf, 3 * HIDDEN * HIDDEN);
    k_cast<<<(3 * HIDDEN * HIDDEN + 255) / 256, 256, 0, stream>>>(W_hh, Whh_bf, 3 * HIDDEN * HIDDEN);
    k_bfold<<<2, 256, 0, stream>>>(b_ih, b_hh, b_fold);

    if (NBsel == 4)
        run_tier<4>(x, W1, b1, W2T_bf, b2, Wih_bf, Whh_bf, b_fold, b_hh, W_out, b_out, out,
                    row_start, csr_src, csr_norm, self_norm, xa, H2all, Z2all, Hf, slots, stream);
    else if (NBsel == 2)
        run_tier<2>(x, W1, b1, W2T_bf, b2, Wih_bf, Whh_bf, b_fold, b_hh, W_out, b_out, out,
                    row_start, csr_src, csr_norm, self_norm, xa, H2all, Z2all, Hf, slots, stream);
    else
        run_tier<1>(x, W1, b1, W2T_bf, b2, Wih_bf, Whh_bf, b_fold, b_hh, W_out, b_out, out,
                    row_start, csr_src, csr_norm, self_norm, xa, H2all, Z2all, Hf, slots, stream);
}